// Round 5
// baseline (300.190 us; speedup 1.0000x reference)
//
#include <hip/hip_runtime.h>
#include <cstdint>
#include <cstddef>

// FeatureAttention: x[4,2048,1024] fp32; Q=xWq^T+bq, K=xWk^T+bk, V=xWv^T+bv;
// out = softmax(QK^T/32) V.  bf16 MFMA pipeline.
//
// R5: (a) tri-fused QKV projection — X staged once, NB=3 weight operands,
// V stored transposed from the C-fragment (kills the separate Vt pass);
// (b) XCD-aware block swizzles (xcd = id%8 heuristic) so each XCD's L2
// holds a compact tile region (R4 FETCH=139MB/pass = cross-XCD replication);
// (c) rowsum stays fused in PV.  4 launches total.
//
// Workspace (80 MB):
//   [0,16M)  Xb    [16,18) Wqb  [18,20) Wkb  [20,22) Wvb   (dead after proj)
//   [32,48M) Qb    [48,64M) Kb   (dead after scores)
//   [64,80M) Vt    (V transposed [1024][8192])
//   [0,32M)  Sc    (exp(scores) bf16 [4][2048][2048], reuses dead region)

typedef unsigned short ushort_t;
typedef __attribute__((ext_vector_type(4))) short short4v;
typedef __attribute__((ext_vector_type(8))) short short8;
typedef __attribute__((ext_vector_type(4))) float f32x4;

#define AS1 __attribute__((address_space(1)))
#define AS3 __attribute__((address_space(3)))

__device__ __forceinline__ ushort_t f2bf(float f) {
    unsigned int u = __float_as_uint(f);
    u += 0x7FFFu + ((u >> 16) & 1u);
    return (ushort_t)(u >> 16);
}
__device__ __forceinline__ float bf2f(ushort_t b) {
    return __uint_as_float(((unsigned)b) << 16);
}

// async global->LDS, 16B/lane; lds dest = wave-uniform base + lane*16
__device__ __forceinline__ void async_ld16(const void* g, unsigned lds_off) {
    __builtin_amdgcn_global_load_lds((const AS1 void*)(uintptr_t)g,
                                     (AS3 void*)(uintptr_t)lds_off,
                                     16, 0, 0);
}

// ---------------------------------------------------------------------------
// BT-GEMM, 128x128 tile, NB outputs sharing the A tile.
//   C_o[m*ldc+n] = epi( scale * sum_k A[m*lda+k] * B_o[n*ldb+k] )
// EPI: 1 +bias_o[n] (NB==3: output 2 stored transposed C2[n*ldc2+m])
//    | 3 exp(v) | 4 v / rowsum(A-tile row m) (rowsum fused in-kernel)
// SWZ block mapping (xcd = id%8 heuristic, s = id/8):
//   1 QKV  (nx=8, ny=64):        by = xcd*8 + s/8,        bx = s%8
//   2 scores (nx=16, ny=16, z):  4m x 8n region per XCD   (WS 3MB < 4MB L2)
//   3 PV   (nx=8, ny=16, z):     4m x 4n region per XCD   (WS 4MB)
// Bank swizzle: 16B chunk c of row r at position (c+r)&(P-1), P=BK/8,
// applied on the staging *source* col (global_load_lds lane->LDS map fixed).
// ---------------------------------------------------------------------------
template <typename OT, int EPI, int NB, int BK, int SWZ>
__global__ __launch_bounds__(256, 2) void gemm_bt(
    const ushort_t* __restrict__ A, const ushort_t* __restrict__ B0,
    const ushort_t* __restrict__ B1, const ushort_t* __restrict__ B2,
    const float* __restrict__ bias0, const float* __restrict__ bias1,
    const float* __restrict__ bias2,
    OT* __restrict__ C0, OT* __restrict__ C1, ushort_t* __restrict__ C2,
    int K, int lda, int ldb, int ldc, int ldc2, float scale,
    long long aOffZ, long long bOffZ, long long cOffZ)
{
    constexpr int P     = BK / 8;
    constexpr int NCALL = BK / 16;
    constexpr int RPC   = 2048 / BK;

    __shared__ __align__(16) ushort_t As[128 * BK];
    __shared__ __align__(16) ushort_t Bs[NB][128 * BK];
    __shared__ float rs[128];

    // ---- block swizzle ----
    int bx, by, bz;
    if (SWZ == 1) {            // 512 blocks
        const int x = blockIdx.x & 7, s = blockIdx.x >> 3;
        by = x * 8 + (s >> 3); bx = s & 7; bz = 0;
    } else if (SWZ == 2) {     // 1024 blocks
        const int id = blockIdx.x; bz = id >> 8;
        const int r = id & 255, x = r & 7, s = r >> 3;
        by = (x >> 1) * 4 + (s & 3); bx = (x & 1) * 8 + (s >> 2);
    } else {                   // SWZ==3, 512 blocks
        const int id = blockIdx.x; bz = id >> 7;
        const int r = id & 127, x = r & 7, s = r >> 3;
        by = (x >> 1) * 4 + (s & 3); bx = (x & 1) * 4 + (s >> 2);
    }

    const int tid  = threadIdx.x;
    const int wave = tid >> 6;
    const int lane = tid & 63;

    A  += (size_t)bz * aOffZ;
    B0 += (size_t)bz * bOffZ;
    if (NB >= 2) B1 += (size_t)bz * bOffZ;

    const int m0 = by * 128;
    const int n0 = bx * 128;
    const int wm = (wave >> 1) * 64;
    const int wn = (wave & 1) * 64;

    const unsigned ldsA  = (unsigned)(uintptr_t)&As[0];
    const unsigned ldsB0 = (unsigned)(uintptr_t)&Bs[0][0];

    // staging map
    const int srow = wave * (RPC / 4) + lane / P;
    const int cd   = ((lane & (P - 1)) - srow) & (P - 1);
    const ushort_t* gA  = A  + (size_t)(m0 + srow) * lda + cd * 8;
    const ushort_t* gB0 = B0 + (size_t)(n0 + srow) * ldb + cd * 8;
    const ushort_t* gB1 = (NB >= 2) ? B1 + (size_t)(n0 + srow) * ldb + cd * 8 : nullptr;
    const ushort_t* gB2 = (NB >= 3) ? B2 + (size_t)(n0 + srow) * ldb + cd * 8 : nullptr;
    const unsigned lw = (wave << 10);
    constexpr unsigned BSTEP = 128 * BK * 2;  // bytes per Bs plane

    // fragment map
    const int frow = lane & 15;
    const int fg   = lane >> 4;

    f32x4 acc[NB][4][4] = {};
    float rsacc[4] = {0.f, 0.f, 0.f, 0.f};

    for (int k0 = 0; k0 < K; k0 += BK) {
        if (k0) __syncthreads();
#pragma unroll
        for (int c = 0; c < NCALL; ++c) {
            const size_t ro = (size_t)c * RPC;
            async_ld16(gA + ro * lda, ldsA + c * 4096 + lw);
            async_ld16(gB0 + ro * ldb, ldsB0 + c * 4096 + lw);
            if (NB >= 2) async_ld16(gB1 + ro * ldb, ldsB0 + BSTEP + c * 4096 + lw);
            if (NB >= 3) async_ld16(gB2 + ro * ldb, ldsB0 + 2 * BSTEP + c * 4096 + lw);
        }
        gA += BK; gB0 += BK;
        if (NB >= 2) gB1 += BK;
        if (NB >= 3) gB2 += BK;
        __syncthreads();

#pragma unroll
        for (int t = 0; t < BK / 32; ++t) {
            const int pa = (((t << 2) + fg + frow) & (P - 1)) << 3;
            short8 af[4], bf[4];
#pragma unroll
            for (int i = 0; i < 4; ++i)
                af[i] = *(const short8*)&As[(wm + i * 16 + frow) * BK + pa];
            if (EPI == 4 && wn == 0) {
#pragma unroll
                for (int i = 0; i < 4; ++i)
#pragma unroll
                    for (int e = 0; e < 8; ++e)
                        rsacc[i] += bf2f((ushort_t)af[i][e]);
            }
#pragma unroll
            for (int o = 0; o < NB; ++o) {
#pragma unroll
                for (int j = 0; j < 4; ++j)
                    bf[j] = *(const short8*)&Bs[o][(wn + j * 16 + frow) * BK + pa];
#pragma unroll
                for (int i = 0; i < 4; ++i)
#pragma unroll
                    for (int j = 0; j < 4; ++j)
                        acc[o][i][j] = __builtin_amdgcn_mfma_f32_16x16x32_bf16(
                            af[i], bf[j], acc[o][i][j], 0, 0, 0);
            }
        }
    }

    if (EPI == 4) {
        if (wn == 0) {
#pragma unroll
            for (int i = 0; i < 4; ++i) {
                float s = rsacc[i];
                s += __shfl_xor(s, 16, 64);
                s += __shfl_xor(s, 32, 64);
                rs[wm + i * 16 + frow] = s;
            }
        }
        __syncthreads();
    }

    // C/D layout: lane l reg r -> row (l>>4)*4+r, col l&15
    const int r0 = (lane >> 4) << 2;
    const int c0 = lane & 15;
    constexpr int NDIR = (NB == 3) ? 2 : NB;   // direct-stored outputs
#pragma unroll
    for (int o = 0; o < NDIR; ++o) {
        OT* C = (o == 0) ? C0 : C1;
        C += (size_t)bz * cOffZ;
        const float* bia = (o == 0) ? bias0 : bias1;
#pragma unroll
        for (int i = 0; i < 4; ++i) {
            float bm[4];
            if (EPI == 4) {
#pragma unroll
                for (int r = 0; r < 4; ++r)
                    bm[r] = 1.0f / rs[wm + i * 16 + r0 + r];
            }
#pragma unroll
            for (int j = 0; j < 4; ++j) {
                const int n = n0 + wn + j * 16 + c0;
                const float bn = (EPI == 1) ? bia[n] : 0.f;
#pragma unroll
                for (int r = 0; r < 4; ++r) {
                    const int m = m0 + wm + i * 16 + r0 + r;
                    float v = acc[o][i][j][r] * scale;
                    if (EPI == 1) v += bn;
                    if (EPI == 3) v = __expf(v);
                    if (EPI == 4) v *= bm[r];
                    if constexpr (sizeof(OT) == 2)
                        C[(size_t)m * ldc + n] = f2bf(v);
                    else
                        C[(size_t)m * ldc + n] = v;
                }
            }
        }
    }
    if (NB == 3) {   // V stored transposed: C2[n*ldc2 + m], 4 m-contig bf16
#pragma unroll
        for (int i = 0; i < 4; ++i) {
#pragma unroll
            for (int j = 0; j < 4; ++j) {
                const int n = n0 + wn + j * 16 + c0;
                const int m = m0 + wm + i * 16 + r0;
                const float bn = bias2[n];
                short4v pk;
#pragma unroll
                for (int r = 0; r < 4; ++r)
                    pk[r] = (short)f2bf(acc[2][i][j][r] + bn);
                *(short4v*)&C2[(size_t)n * ldc2 + m] = pk;
            }
        }
    }
}

// one-shot fp32->bf16 cast of x, Wq, Wk, Wv (block-range dispatch)
__global__ __launch_bounds__(256) void cvt_all(
    const float* __restrict__ x,  const float* __restrict__ wq,
    const float* __restrict__ wk, const float* __restrict__ wv,
    ushort_t* __restrict__ xb,  ushort_t* __restrict__ wqb,
    ushort_t* __restrict__ wkb, ushort_t* __restrict__ wvb)
{
    const int b = blockIdx.x;
    const float* src; ushort_t* dst; size_t base;
    if (b < 4096)      { src = x;  dst = xb;  base = (size_t)b * 2048; }
    else if (b < 4608) { src = wq; dst = wqb; base = (size_t)(b - 4096) * 2048; }
    else if (b < 5120) { src = wk; dst = wkb; base = (size_t)(b - 4608) * 2048; }
    else               { src = wv; dst = wvb; base = (size_t)(b - 5120) * 2048; }
    const size_t i = base + threadIdx.x * 8;
    const f32x4 a = *(const f32x4*)(src + i);
    const f32x4 c = *(const f32x4*)(src + i + 4);
    short8 o;
    o[0] = (short)f2bf(a[0]); o[1] = (short)f2bf(a[1]);
    o[2] = (short)f2bf(a[2]); o[3] = (short)f2bf(a[3]);
    o[4] = (short)f2bf(c[0]); o[5] = (short)f2bf(c[1]);
    o[6] = (short)f2bf(c[2]); o[7] = (short)f2bf(c[3]);
    *(short8*)(dst + i) = o;
}

extern "C" void kernel_launch(void* const* d_in, const int* in_sizes, int n_in,
                              void* d_out, int out_size, void* d_ws, size_t ws_size,
                              hipStream_t stream)
{
    const float* x  = (const float*)d_in[0];
    const float* Wq = (const float*)d_in[1];
    const float* bq = (const float*)d_in[2];
    const float* Wk = (const float*)d_in[3];
    const float* bk = (const float*)d_in[4];
    const float* Wv = (const float*)d_in[5];
    const float* bv = (const float*)d_in[6];
    float* out = (float*)d_out;

    char* ws = (char*)d_ws;
    const size_t MB = 1ull << 20;
    ushort_t* Xb  = (ushort_t*)(ws);
    ushort_t* Wqb = (ushort_t*)(ws + 16 * MB);
    ushort_t* Wkb = (ushort_t*)(ws + 18 * MB);
    ushort_t* Wvb = (ushort_t*)(ws + 20 * MB);
    ushort_t* Qb  = (ushort_t*)(ws + 32 * MB);
    ushort_t* Kb  = (ushort_t*)(ws + 48 * MB);
    ushort_t* Vt  = (ushort_t*)(ws + 64 * MB);
    ushort_t* Sc  = (ushort_t*)(ws);             // reuses dead Xb/W region

    // 1) all casts in one launch
    cvt_all<<<dim3(5632), dim3(256), 0, stream>>>(
        x, Wq, Wk, Wv, Xb, Wqb, Wkb, Wvb);

    // 2) tri-fused Q,K,V projection (V -> Vt transposed)
    gemm_bt<ushort_t, 1, 3, 64, 1><<<dim3(512), dim3(256), 0, stream>>>(
        Xb, Wqb, Wkb, Wvb, bq, bk, bv, Qb, Kb, Vt,
        1024, 1024, 1024, 1024, 8192, 1.0f, 0, 0, 0);

    // 3) Sc = exp(Q K^T / 32) per batch (max-free softmax numerator)
    gemm_bt<ushort_t, 3, 1, 64, 2><<<dim3(1024), dim3(256), 0, stream>>>(
        Qb, Kb, nullptr, nullptr, nullptr, nullptr, nullptr, Sc, nullptr, nullptr,
        1024, 1024, 1024, 2048, 0, 0.03125f,
        2048ll * 1024, 2048ll * 1024, 2048ll * 2048);

    // 4) out = (Sc Vt^T) / rowsum(Sc row), rowsum fused in-kernel
    gemm_bt<float, 4, 1, 64, 3><<<dim3(512), dim3(256), 0, stream>>>(
        Sc, Vt, nullptr, nullptr, nullptr, nullptr, nullptr, out, nullptr, nullptr,
        2048, 2048, 8192, 1024, 0, 1.0f,
        2048ll * 2048, 2048ll, 2048ll * 1024);
}

// Round 6
// 267.888 us; speedup vs baseline: 1.1206x; 1.1206x over previous
//
#include <hip/hip_runtime.h>
#include <cstdint>
#include <cstddef>

// FeatureAttention: x[4,2048,1024] fp32; Q=xWq^T+bq, K=xWk^T+bk, V=xWv^T+bv;
// out = softmax(QK^T/32) V.  bf16 MFMA pipeline.
//
// R6: tri-fused QKV redone with 512-thread blocks so the accumulator fits:
// 8 waves x (4m x 2n tiles x 3 outputs) = 96 acc VGPR/wave (R5's 256-thread
// version needed 192 and spilled -> 132MB of scratch writes).  XCD swizzle
// from R5 dropped (it cost scores+PV ~50us vs R4's linear grid).
//
// Workspace (80 MB):
//   [0,16M)  Xb    [16,18) Wqb  [18,20) Wkb  [20,22) Wvb   (dead after proj)
//   [32,48M) Qb    [48,64M) Kb   (dead after scores)
//   [64,80M) Vt    (V transposed [1024][8192])
//   [0,32M)  Sc    (exp(scores) bf16 [4][2048][2048], reuses dead region)

typedef unsigned short ushort_t;
typedef __attribute__((ext_vector_type(4))) short short4v;
typedef __attribute__((ext_vector_type(8))) short short8;
typedef __attribute__((ext_vector_type(4))) float f32x4;

#define AS1 __attribute__((address_space(1)))
#define AS3 __attribute__((address_space(3)))

__device__ __forceinline__ ushort_t f2bf(float f) {
    unsigned int u = __float_as_uint(f);
    u += 0x7FFFu + ((u >> 16) & 1u);
    return (ushort_t)(u >> 16);
}
__device__ __forceinline__ float bf2f(ushort_t b) {
    return __uint_as_float(((unsigned)b) << 16);
}

// async global->LDS, 16B/lane; lds dest = WAVE-uniform base + lane*16
__device__ __forceinline__ void async_ld16(const void* g, unsigned lds_off) {
    __builtin_amdgcn_global_load_lds((const AS1 void*)(uintptr_t)g,
                                     (AS3 void*)(uintptr_t)lds_off,
                                     16, 0, 0);
}

// ---------------------------------------------------------------------------
// QKV tri-fused projection.  512 threads (8 waves), 128x128 tile, BK=64.
// Wave tile: 64m x 32n (4 x 2 MFMA tiles) per output => acc 96 VGPR.
// X staged once per K-iter, 3 weight planes.  Q,K stored [m,1024]+bias[n];
// V stored transposed Vt[n*8192+m]+bias[n] (4 m-contig bf16 per store).
// Bank swizzle: 16B chunk at row r, position p holds source chunk (p-r)&7.
// ---------------------------------------------------------------------------
__global__ __launch_bounds__(512, 2) void qkv_gemm(
    const ushort_t* __restrict__ X,
    const ushort_t* __restrict__ W0, const ushort_t* __restrict__ W1,
    const ushort_t* __restrict__ W2,
    const float* __restrict__ b0, const float* __restrict__ b1,
    const float* __restrict__ b2,
    ushort_t* __restrict__ Q, ushort_t* __restrict__ Kout,
    ushort_t* __restrict__ Vt)
{
    __shared__ __align__(16) ushort_t As[128 * 64];      // 16 KB
    __shared__ __align__(16) ushort_t Bs[3][128 * 64];   // 48 KB

    const int tid  = threadIdx.x;
    const int wave = tid >> 6;
    const int lane = tid & 63;

    const int m0 = blockIdx.y * 128;
    const int n0 = blockIdx.x * 128;
    const int wm = (wave >> 2) * 64;         // 0 / 64
    const int wn = (wave & 3) * 32;          // 0 / 32 / 64 / 96

    const unsigned ldsA = (unsigned)(uintptr_t)&As[0];
    const unsigned ldsB = (unsigned)(uintptr_t)&Bs[0][0];
    constexpr unsigned BSTEP = 128 * 64 * 2;

    // staging: call c covers rows [c*64, +64); wave w rows w*8..+8
    const int srow = (wave << 3) + (lane >> 3);          // row within call
    const int cd   = ((lane & 7) - (lane >> 3)) & 7;     // swizzled src chunk
    const ushort_t* gX  = X  + (size_t)(m0 + srow) * 1024 + cd * 8;
    const ushort_t* gW0 = W0 + (size_t)(n0 + srow) * 1024 + cd * 8;
    const ushort_t* gW1 = W1 + (size_t)(n0 + srow) * 1024 + cd * 8;
    const ushort_t* gW2 = W2 + (size_t)(n0 + srow) * 1024 + cd * 8;
    const unsigned lw = (wave << 10);        // wave-uniform LDS base offset

    const int frow = lane & 15;
    const int fg   = lane >> 4;

    f32x4 acc[3][4][2] = {};

    for (int k0 = 0; k0 < 1024; k0 += 64) {
        if (k0) __syncthreads();
#pragma unroll
        for (int c = 0; c < 2; ++c) {
            const size_t ro = (size_t)c * 64;
            async_ld16(gX  + ro * 1024, ldsA + c * 8192 + lw);
            async_ld16(gW0 + ro * 1024, ldsB + 0 * BSTEP + c * 8192 + lw);
            async_ld16(gW1 + ro * 1024, ldsB + 1 * BSTEP + c * 8192 + lw);
            async_ld16(gW2 + ro * 1024, ldsB + 2 * BSTEP + c * 8192 + lw);
        }
        gX += 64; gW0 += 64; gW1 += 64; gW2 += 64;
        __syncthreads();

#pragma unroll
        for (int t = 0; t < 2; ++t) {
            const int ck = (t << 2) + fg;
            short8 af[4], bf[2];
#pragma unroll
            for (int i = 0; i < 4; ++i) {
                const int row = wm + i * 16 + frow;
                af[i] = *(const short8*)&As[row * 64 + (((ck + row) & 7) << 3)];
            }
#pragma unroll
            for (int o = 0; o < 3; ++o) {
#pragma unroll
                for (int j = 0; j < 2; ++j) {
                    const int row = wn + j * 16 + frow;
                    bf[j] = *(const short8*)&Bs[o][row * 64 + (((ck + row) & 7) << 3)];
                }
#pragma unroll
                for (int i = 0; i < 4; ++i)
#pragma unroll
                    for (int j = 0; j < 2; ++j)
                        acc[o][i][j] = __builtin_amdgcn_mfma_f32_16x16x32_bf16(
                            af[i], bf[j], acc[o][i][j], 0, 0, 0);
            }
        }
    }

    // C/D layout: lane l reg r -> row (l>>4)*4+r, col l&15
    const int r0 = (lane >> 4) << 2;
    const int c0 = lane & 15;
#pragma unroll
    for (int o = 0; o < 2; ++o) {            // Q, K direct
        ushort_t* C = (o == 0) ? Q : Kout;
        const float* bia = (o == 0) ? b0 : b1;
#pragma unroll
        for (int i = 0; i < 4; ++i) {
#pragma unroll
            for (int j = 0; j < 2; ++j) {
                const int n = n0 + wn + j * 16 + c0;
                const float bn = bia[n];
#pragma unroll
                for (int r = 0; r < 4; ++r) {
                    const int m = m0 + wm + i * 16 + r0 + r;
                    C[(size_t)m * 1024 + n] = f2bf(acc[o][i][j][r] + bn);
                }
            }
        }
    }
#pragma unroll
    for (int i = 0; i < 4; ++i) {            // V transposed
#pragma unroll
        for (int j = 0; j < 2; ++j) {
            const int n = n0 + wn + j * 16 + c0;
            const int m = m0 + wm + i * 16 + r0;
            const float bn = b2[n];
            short4v pk;
#pragma unroll
            for (int r = 0; r < 4; ++r)
                pk[r] = (short)f2bf(acc[2][i][j][r] + bn);
            *(short4v*)&Vt[(size_t)n * 8192 + m] = pk;
        }
    }
}

// ---------------------------------------------------------------------------
// BT-GEMM (R4-proven), 256 threads, 128x128 tile, BK=64, linear grid.
//   C[m*ldc+n] = epi( scale * sum_k A[m*lda+k] * B[n*ldb+k] )
// EPI: 3 exp(v) | 4 v / rowsum(A-tile row m) (rowsum fused in-kernel)
// ---------------------------------------------------------------------------
template <typename OT, int EPI>
__global__ __launch_bounds__(256, 2) void gemm_bt(
    const ushort_t* __restrict__ A, const ushort_t* __restrict__ B0,
    OT* __restrict__ C0,
    int K, int lda, int ldb, int ldc, float scale,
    long long aOffZ, long long bOffZ, long long cOffZ)
{
    constexpr int BK = 64, P = 8, NCALL = 4, RPC = 32;

    __shared__ __align__(16) ushort_t As[128 * BK];
    __shared__ __align__(16) ushort_t Bs[128 * BK];
    __shared__ float rs[128];

    const int tid  = threadIdx.x;
    const int wave = tid >> 6;
    const int lane = tid & 63;

    A  += (size_t)blockIdx.z * aOffZ;
    B0 += (size_t)blockIdx.z * bOffZ;

    const int m0 = blockIdx.y * 128;
    const int n0 = blockIdx.x * 128;
    const int wm = (wave >> 1) * 64;
    const int wn = (wave & 1) * 64;

    const unsigned ldsA = (unsigned)(uintptr_t)&As[0];
    const unsigned ldsB = (unsigned)(uintptr_t)&Bs[0];

    const int srow = wave * (RPC / 4) + lane / P;
    const int cd   = ((lane & (P - 1)) - srow) & (P - 1);
    const ushort_t* gA  = A  + (size_t)(m0 + srow) * lda + cd * 8;
    const ushort_t* gB0 = B0 + (size_t)(n0 + srow) * ldb + cd * 8;
    const unsigned lw = (wave << 10);

    const int frow = lane & 15;
    const int fg   = lane >> 4;

    f32x4 acc[4][4] = {};
    float rsacc[4] = {0.f, 0.f, 0.f, 0.f};

    for (int k0 = 0; k0 < K; k0 += BK) {
        if (k0) __syncthreads();
#pragma unroll
        for (int c = 0; c < NCALL; ++c) {
            const size_t ro = (size_t)c * RPC;
            async_ld16(gA + ro * lda, ldsA + c * 4096 + lw);
            async_ld16(gB0 + ro * ldb, ldsB + c * 4096 + lw);
        }
        gA += BK; gB0 += BK;
        __syncthreads();

#pragma unroll
        for (int t = 0; t < 2; ++t) {
            const int pa = (((t << 2) + fg + frow) & (P - 1)) << 3;
            short8 af[4], bf[4];
#pragma unroll
            for (int i = 0; i < 4; ++i)
                af[i] = *(const short8*)&As[(wm + i * 16 + frow) * BK + pa];
            if (EPI == 4 && wn == 0) {
#pragma unroll
                for (int i = 0; i < 4; ++i)
#pragma unroll
                    for (int e = 0; e < 8; ++e)
                        rsacc[i] += bf2f((ushort_t)af[i][e]);
            }
#pragma unroll
            for (int j = 0; j < 4; ++j)
                bf[j] = *(const short8*)&Bs[(wn + j * 16 + frow) * BK + pa];
#pragma unroll
            for (int i = 0; i < 4; ++i)
#pragma unroll
                for (int j = 0; j < 4; ++j)
                    acc[i][j] = __builtin_amdgcn_mfma_f32_16x16x32_bf16(
                        af[i], bf[j], acc[i][j], 0, 0, 0);
        }
    }

    if (EPI == 4) {
        if (wn == 0) {
#pragma unroll
            for (int i = 0; i < 4; ++i) {
                float s = rsacc[i];
                s += __shfl_xor(s, 16, 64);
                s += __shfl_xor(s, 32, 64);
                rs[wm + i * 16 + frow] = s;
            }
        }
        __syncthreads();
    }

    const int r0 = (lane >> 4) << 2;
    const int c0 = lane & 15;
    OT* C = C0 + (size_t)blockIdx.z * cOffZ;
#pragma unroll
    for (int i = 0; i < 4; ++i) {
        float bm[4];
        if (EPI == 4) {
#pragma unroll
            for (int r = 0; r < 4; ++r)
                bm[r] = 1.0f / rs[wm + i * 16 + r0 + r];
        }
#pragma unroll
        for (int j = 0; j < 4; ++j) {
            const int n = n0 + wn + j * 16 + c0;
#pragma unroll
            for (int r = 0; r < 4; ++r) {
                const int m = m0 + wm + i * 16 + r0 + r;
                float v = acc[i][j][r] * scale;
                if (EPI == 3) v = __expf(v);
                if (EPI == 4) v *= bm[r];
                if constexpr (sizeof(OT) == 2)
                    C[(size_t)m * ldc + n] = f2bf(v);
                else
                    C[(size_t)m * ldc + n] = v;
            }
        }
    }
}

// one-shot fp32->bf16 cast of x, Wq, Wk, Wv (block-range dispatch)
__global__ __launch_bounds__(256) void cvt_all(
    const float* __restrict__ x,  const float* __restrict__ wq,
    const float* __restrict__ wk, const float* __restrict__ wv,
    ushort_t* __restrict__ xb,  ushort_t* __restrict__ wqb,
    ushort_t* __restrict__ wkb, ushort_t* __restrict__ wvb)
{
    const int b = blockIdx.x;
    const float* src; ushort_t* dst; size_t base;
    if (b < 4096)      { src = x;  dst = xb;  base = (size_t)b * 2048; }
    else if (b < 4608) { src = wq; dst = wqb; base = (size_t)(b - 4096) * 2048; }
    else if (b < 5120) { src = wk; dst = wkb; base = (size_t)(b - 4608) * 2048; }
    else               { src = wv; dst = wvb; base = (size_t)(b - 5120) * 2048; }
    const size_t i = base + threadIdx.x * 8;
    const f32x4 a = *(const f32x4*)(src + i);
    const f32x4 c = *(const f32x4*)(src + i + 4);
    short8 o;
    o[0] = (short)f2bf(a[0]); o[1] = (short)f2bf(a[1]);
    o[2] = (short)f2bf(a[2]); o[3] = (short)f2bf(a[3]);
    o[4] = (short)f2bf(c[0]); o[5] = (short)f2bf(c[1]);
    o[6] = (short)f2bf(c[2]); o[7] = (short)f2bf(c[3]);
    *(short8*)(dst + i) = o;
}

extern "C" void kernel_launch(void* const* d_in, const int* in_sizes, int n_in,
                              void* d_out, int out_size, void* d_ws, size_t ws_size,
                              hipStream_t stream)
{
    const float* x  = (const float*)d_in[0];
    const float* Wq = (const float*)d_in[1];
    const float* bq = (const float*)d_in[2];
    const float* Wk = (const float*)d_in[3];
    const float* bk = (const float*)d_in[4];
    const float* Wv = (const float*)d_in[5];
    const float* bv = (const float*)d_in[6];
    float* out = (float*)d_out;

    char* ws = (char*)d_ws;
    const size_t MB = 1ull << 20;
    ushort_t* Xb  = (ushort_t*)(ws);
    ushort_t* Wqb = (ushort_t*)(ws + 16 * MB);
    ushort_t* Wkb = (ushort_t*)(ws + 18 * MB);
    ushort_t* Wvb = (ushort_t*)(ws + 20 * MB);
    ushort_t* Qb  = (ushort_t*)(ws + 32 * MB);
    ushort_t* Kb  = (ushort_t*)(ws + 48 * MB);
    ushort_t* Vt  = (ushort_t*)(ws + 64 * MB);
    ushort_t* Sc  = (ushort_t*)(ws);             // reuses dead Xb/W region

    // 1) all casts in one launch
    cvt_all<<<dim3(5632), dim3(256), 0, stream>>>(
        x, Wq, Wk, Wv, Xb, Wqb, Wkb, Wvb);

    // 2) tri-fused Q,K,V projection (V -> Vt transposed), 512-thread blocks
    qkv_gemm<<<dim3(8, 64), dim3(512), 0, stream>>>(
        Xb, Wqb, Wkb, Wvb, bq, bk, bv, Qb, Kb, Vt);

    // 3) Sc = exp(Q K^T / 32) per batch (max-free softmax numerator)
    gemm_bt<ushort_t, 3><<<dim3(16, 16, 4), dim3(256), 0, stream>>>(
        Qb, Kb, Sc, 1024, 1024, 1024, 2048, 0.03125f,
        2048ll * 1024, 2048ll * 1024, 2048ll * 2048);

    // 4) out = (Sc Vt^T) / rowsum(Sc row), rowsum fused in-kernel
    gemm_bt<float, 4><<<dim3(8, 16, 4), dim3(256), 0, stream>>>(
        Sc, Vt, out, 2048, 2048, 8192, 1024, 1.0f,
        2048ll * 2048, 2048ll, 2048ll * 1024);
}

// Round 7
// 256.988 us; speedup vs baseline: 1.1681x; 1.0424x over previous
//
#include <hip/hip_runtime.h>
#include <cstdint>
#include <cstddef>

// FeatureAttention: x[4,2048,1024] fp32; Q=xWq^T+bq, K=xWk^T+bk, V=xWv^T+bv;
// out = softmax(QK^T/32) V.
//
// R7: Q/K stored as fp8 e4m3 (qkv epilogue pack) and scores GEMM runs on
// mfma_f32_16x16x32_fp8_fp8 — same MFMA rate as bf16, half the staging/fetch
// bytes (per-batch Q+K working set 8->4 MB, fits one XCD L2).  attn & V stay
// bf16 (fp8 there would add ~4.6e-4 sigma — over budget).  PV keeps fused
// rowsum; no grid swizzles (R5 measured them negative).
//
// Workspace (80 MB):
//   [0,16M)  Xb    [16,18) Wqb  [18,20) Wkb  [20,22) Wvb   (dead after proj)
//   [32,40M) Q8 fp8   [40,48M) K8 fp8    (dead after scores)
//   [64,80M) Vt bf16  (V transposed [1024][8192])
//   [0,32M)  Sc bf16  (exp(scores) [4][2048][2048], reuses dead region)

typedef unsigned short ushort_t;
typedef unsigned char u8;
typedef __attribute__((ext_vector_type(4))) short short4v;
typedef __attribute__((ext_vector_type(8))) short short8;
typedef __attribute__((ext_vector_type(4))) float f32x4;

#define AS1 __attribute__((address_space(1)))
#define AS3 __attribute__((address_space(3)))

__device__ __forceinline__ ushort_t f2bf(float f) {
    unsigned int u = __float_as_uint(f);
    u += 0x7FFFu + ((u >> 16) & 1u);
    return (ushort_t)(u >> 16);
}
__device__ __forceinline__ float bf2f(ushort_t b) {
    return __uint_as_float(((unsigned)b) << 16);
}

// async global->LDS, 16B/lane; lds dest = WAVE-uniform base + lane*16
__device__ __forceinline__ void async_ld16(const void* g, unsigned lds_off) {
    __builtin_amdgcn_global_load_lds((const AS1 void*)(uintptr_t)g,
                                     (AS3 void*)(uintptr_t)lds_off,
                                     16, 0, 0);
}

// ---------------------------------------------------------------------------
// QKV tri-fused projection.  512 threads (8 waves), 128x128 tile, BK=64.
// Wave tile: 64m x 32n per output => acc 96 VGPR (R6-proven, no spills).
// Q,K stored fp8 e4m3 [m][1024]; V stored transposed bf16 Vt[n*8192+m].
// Bank swizzle: 16B chunk at row r, position p holds source chunk (p-r)&7.
// ---------------------------------------------------------------------------
__global__ __launch_bounds__(512, 2) void qkv_gemm(
    const ushort_t* __restrict__ X,
    const ushort_t* __restrict__ W0, const ushort_t* __restrict__ W1,
    const ushort_t* __restrict__ W2,
    const float* __restrict__ b0, const float* __restrict__ b1,
    const float* __restrict__ b2,
    u8* __restrict__ Q8, u8* __restrict__ K8, ushort_t* __restrict__ Vt)
{
    __shared__ __align__(16) ushort_t As[128 * 64];      // 16 KB
    __shared__ __align__(16) ushort_t Bs[3][128 * 64];   // 48 KB

    const int tid  = threadIdx.x;
    const int wave = tid >> 6;
    const int lane = tid & 63;

    const int m0 = blockIdx.y * 128;
    const int n0 = blockIdx.x * 128;
    const int wm = (wave >> 2) * 64;
    const int wn = (wave & 3) * 32;

    const unsigned ldsA = (unsigned)(uintptr_t)&As[0];
    const unsigned ldsB = (unsigned)(uintptr_t)&Bs[0][0];
    constexpr unsigned BSTEP = 128 * 64 * 2;

    const int srow = (wave << 3) + (lane >> 3);
    const int cd   = ((lane & 7) - (lane >> 3)) & 7;
    const ushort_t* gX  = X  + (size_t)(m0 + srow) * 1024 + cd * 8;
    const ushort_t* gW0 = W0 + (size_t)(n0 + srow) * 1024 + cd * 8;
    const ushort_t* gW1 = W1 + (size_t)(n0 + srow) * 1024 + cd * 8;
    const ushort_t* gW2 = W2 + (size_t)(n0 + srow) * 1024 + cd * 8;
    const unsigned lw = (wave << 10);

    const int frow = lane & 15;
    const int fg   = lane >> 4;

    f32x4 acc[3][4][2] = {};

    for (int k0 = 0; k0 < 1024; k0 += 64) {
        if (k0) __syncthreads();
#pragma unroll
        for (int c = 0; c < 2; ++c) {
            const size_t ro = (size_t)c * 64;
            async_ld16(gX  + ro * 1024, ldsA + c * 8192 + lw);
            async_ld16(gW0 + ro * 1024, ldsB + 0 * BSTEP + c * 8192 + lw);
            async_ld16(gW1 + ro * 1024, ldsB + 1 * BSTEP + c * 8192 + lw);
            async_ld16(gW2 + ro * 1024, ldsB + 2 * BSTEP + c * 8192 + lw);
        }
        gX += 64; gW0 += 64; gW1 += 64; gW2 += 64;
        __syncthreads();

#pragma unroll
        for (int t = 0; t < 2; ++t) {
            const int ck = (t << 2) + fg;
            short8 af[4], bf[2];
#pragma unroll
            for (int i = 0; i < 4; ++i) {
                const int row = wm + i * 16 + frow;
                af[i] = *(const short8*)&As[row * 64 + (((ck + row) & 7) << 3)];
            }
#pragma unroll
            for (int o = 0; o < 3; ++o) {
#pragma unroll
                for (int j = 0; j < 2; ++j) {
                    const int row = wn + j * 16 + frow;
                    bf[j] = *(const short8*)&Bs[o][row * 64 + (((ck + row) & 7) << 3)];
                }
#pragma unroll
                for (int i = 0; i < 4; ++i)
#pragma unroll
                    for (int j = 0; j < 2; ++j)
                        acc[o][i][j] = __builtin_amdgcn_mfma_f32_16x16x32_bf16(
                            af[i], bf[j], acc[o][i][j], 0, 0, 0);
            }
        }
    }

    // C/D layout: lane l reg r -> row (l>>4)*4+r, col l&15
    const int r0 = (lane >> 4) << 2;
    const int c0 = lane & 15;
#pragma unroll
    for (int o = 0; o < 2; ++o) {            // Q, K -> fp8 e4m3
        u8* C = (o == 0) ? Q8 : K8;
        const float* bia = (o == 0) ? b0 : b1;
#pragma unroll
        for (int i = 0; i < 4; ++i) {
#pragma unroll
            for (int j = 0; j < 2; ++j) {
                const int n = n0 + wn + j * 16 + c0;
                const float bn = bia[n];
                const int p0 = __builtin_amdgcn_cvt_pk_fp8_f32(
                    acc[o][i][j][0] + bn, acc[o][i][j][1] + bn, 0, false);
                const int p1 = __builtin_amdgcn_cvt_pk_fp8_f32(
                    acc[o][i][j][2] + bn, acc[o][i][j][3] + bn, 0, false);
                const size_t mb = (size_t)(m0 + wm + i * 16 + r0);
                C[(mb + 0) * 1024 + n] = (u8)(p0 & 0xFF);
                C[(mb + 1) * 1024 + n] = (u8)((p0 >> 8) & 0xFF);
                C[(mb + 2) * 1024 + n] = (u8)(p1 & 0xFF);
                C[(mb + 3) * 1024 + n] = (u8)((p1 >> 8) & 0xFF);
            }
        }
    }
#pragma unroll
    for (int i = 0; i < 4; ++i) {            // V transposed, bf16
#pragma unroll
        for (int j = 0; j < 2; ++j) {
            const int n = n0 + wn + j * 16 + c0;
            const int m = m0 + wm + i * 16 + r0;
            const float bn = b2[n];
            short4v pk;
#pragma unroll
            for (int r = 0; r < 4; ++r)
                pk[r] = (short)f2bf(acc[2][i][j][r] + bn);
            *(short4v*)&Vt[(size_t)n * 8192 + m] = pk;
        }
    }
}

// ---------------------------------------------------------------------------
// Scores: Sc = exp(Q K^T / 32), fp8 e4m3 operands, 128x128 tile, BK=64.
// LDS rows 64 B, P=4 16B-chunks, swizzle pos=(chunk+row)&3.  Fragment:
// lane l -> row l&15, k = t*32 + (l>>4)*8 .. +8 (8 B ds_read).
// ---------------------------------------------------------------------------
__global__ __launch_bounds__(256, 2) void qk_fp8(
    const u8* __restrict__ Q8, const u8* __restrict__ K8,
    ushort_t* __restrict__ Sc)
{
    __shared__ __align__(16) u8 As[128 * 64];   // 8 KB
    __shared__ __align__(16) u8 Bs[128 * 64];   // 8 KB

    const int tid  = threadIdx.x;
    const int wave = tid >> 6;
    const int lane = tid & 63;

    const u8* A = Q8 + (size_t)blockIdx.z * 2048 * 1024;
    const u8* B = K8 + (size_t)blockIdx.z * 2048 * 1024;

    const int m0 = blockIdx.y * 128;
    const int n0 = blockIdx.x * 128;
    const int wm = (wave >> 1) * 64;
    const int wn = (wave & 1) * 64;

    const unsigned ldsA = (unsigned)(uintptr_t)&As[0];
    const unsigned ldsB = (unsigned)(uintptr_t)&Bs[0];

    // staging: call covers 64 rows; wave w rows w*16 + lane/4
    const int srow = (wave << 4) + (lane >> 2);
    const int cd   = ((lane & 3) - srow) & 3;
    const u8* gA = A + (size_t)(m0 + srow) * 1024 + cd * 16;
    const u8* gB = B + (size_t)(n0 + srow) * 1024 + cd * 16;
    const unsigned lw = (wave << 10);

    const int frow = lane & 15;
    const int fg   = lane >> 4;

    f32x4 acc[4][4] = {};

    for (int k0 = 0; k0 < 1024; k0 += 64) {
        if (k0) __syncthreads();
        async_ld16(gA,             ldsA + lw);
        async_ld16(gA + 64 * 1024, ldsA + 4096 + lw);
        async_ld16(gB,             ldsB + lw);
        async_ld16(gB + 64 * 1024, ldsB + 4096 + lw);
        gA += 64; gB += 64;
        __syncthreads();

#pragma unroll
        for (int t = 0; t < 2; ++t) {
            const int ck = (t << 1) + (fg >> 1);
            const int io = (fg & 1) << 3;
            long long af[4], bf[4];
#pragma unroll
            for (int i = 0; i < 4; ++i) {
                const int row = wm + i * 16 + frow;
                af[i] = *(const long long*)&As[row * 64 + (((ck + row) & 3) << 4) + io];
            }
#pragma unroll
            for (int j = 0; j < 4; ++j) {
                const int row = wn + j * 16 + frow;
                bf[j] = *(const long long*)&Bs[row * 64 + (((ck + row) & 3) << 4) + io];
            }
#pragma unroll
            for (int i = 0; i < 4; ++i)
#pragma unroll
                for (int j = 0; j < 4; ++j)
                    acc[i][j] = __builtin_amdgcn_mfma_f32_16x16x32_fp8_fp8(
                        af[i], bf[j], acc[i][j], 0, 0, 0);
        }
    }

    const int r0 = (lane >> 4) << 2;
    const int c0 = lane & 15;
    ushort_t* C = Sc + (size_t)blockIdx.z * 2048 * 2048;
#pragma unroll
    for (int i = 0; i < 4; ++i)
#pragma unroll
        for (int j = 0; j < 4; ++j) {
            const int n = n0 + wn + j * 16 + c0;
#pragma unroll
            for (int r = 0; r < 4; ++r) {
                const int m = m0 + wm + i * 16 + r0 + r;
                C[(size_t)m * 2048 + n] = f2bf(__expf(acc[i][j][r] * 0.03125f));
            }
        }
}

// ---------------------------------------------------------------------------
// PV (R4-proven): out = (Sc Vt^T) / rowsum(Sc row); bf16, BK=64, rowsum fused.
// ---------------------------------------------------------------------------
__global__ __launch_bounds__(256, 2) void pv_gemm(
    const ushort_t* __restrict__ A, const ushort_t* __restrict__ B0,
    float* __restrict__ C0)
{
    constexpr int BK = 64, P = 8;

    __shared__ __align__(16) ushort_t As[128 * BK];
    __shared__ __align__(16) ushort_t Bs[128 * BK];
    __shared__ float rs[128];

    const int tid  = threadIdx.x;
    const int wave = tid >> 6;
    const int lane = tid & 63;

    A += (size_t)blockIdx.z * 2048 * 2048;
    const ushort_t* B = B0 + (size_t)blockIdx.z * 2048;

    const int m0 = blockIdx.y * 128;
    const int n0 = blockIdx.x * 128;
    const int wm = (wave >> 1) * 64;
    const int wn = (wave & 1) * 64;

    const unsigned ldsA = (unsigned)(uintptr_t)&As[0];
    const unsigned ldsB = (unsigned)(uintptr_t)&Bs[0];

    const int srow = wave * 8 + lane / P;
    const int cd   = ((lane & (P - 1)) - srow) & (P - 1);
    const ushort_t* gA = A + (size_t)(m0 + srow) * 2048 + cd * 8;
    const ushort_t* gB = B + (size_t)(n0 + srow) * 8192 + cd * 8;
    const unsigned lw = (wave << 10);

    const int frow = lane & 15;
    const int fg   = lane >> 4;

    f32x4 acc[4][4] = {};
    float rsacc[4] = {0.f, 0.f, 0.f, 0.f};

    for (int k0 = 0; k0 < 2048; k0 += BK) {
        if (k0) __syncthreads();
#pragma unroll
        for (int c = 0; c < 4; ++c) {
            const size_t ro = (size_t)c * 32;
            async_ld16(gA + ro * 2048, ldsA + c * 4096 + lw);
            async_ld16(gB + ro * 8192, ldsB + c * 4096 + lw);
        }
        gA += BK; gB += BK;
        __syncthreads();

#pragma unroll
        for (int t = 0; t < 2; ++t) {
            const int pa = (((t << 2) + fg + frow) & (P - 1)) << 3;
            short8 af[4], bf[4];
#pragma unroll
            for (int i = 0; i < 4; ++i)
                af[i] = *(const short8*)&As[(wm + i * 16 + frow) * BK + pa];
            if (wn == 0) {
#pragma unroll
                for (int i = 0; i < 4; ++i)
#pragma unroll
                    for (int e = 0; e < 8; ++e)
                        rsacc[i] += bf2f((ushort_t)af[i][e]);
            }
#pragma unroll
            for (int j = 0; j < 4; ++j)
                bf[j] = *(const short8*)&Bs[(wn + j * 16 + frow) * BK + pa];
#pragma unroll
            for (int i = 0; i < 4; ++i)
#pragma unroll
                for (int j = 0; j < 4; ++j)
                    acc[i][j] = __builtin_amdgcn_mfma_f32_16x16x32_bf16(
                        af[i], bf[j], acc[i][j], 0, 0, 0);
        }
    }

    if (wn == 0) {
#pragma unroll
        for (int i = 0; i < 4; ++i) {
            float s = rsacc[i];
            s += __shfl_xor(s, 16, 64);
            s += __shfl_xor(s, 32, 64);
            rs[wm + i * 16 + frow] = s;
        }
    }
    __syncthreads();

    const int r0 = (lane >> 4) << 2;
    const int c0 = lane & 15;
    float* C = C0 + (size_t)blockIdx.z * 2048 * 1024;
#pragma unroll
    for (int i = 0; i < 4; ++i) {
        float bm[4];
#pragma unroll
        for (int r = 0; r < 4; ++r)
            bm[r] = 1.0f / rs[wm + i * 16 + r0 + r];
#pragma unroll
        for (int j = 0; j < 4; ++j) {
            const int n = n0 + wn + j * 16 + c0;
#pragma unroll
            for (int r = 0; r < 4; ++r) {
                const int m = m0 + wm + i * 16 + r0 + r;
                C[(size_t)m * 1024 + n] = acc[i][j][r] * bm[r];
            }
        }
    }
}

// one-shot fp32->bf16 cast of x, Wq, Wk, Wv (block-range dispatch)
__global__ __launch_bounds__(256) void cvt_all(
    const float* __restrict__ x,  const float* __restrict__ wq,
    const float* __restrict__ wk, const float* __restrict__ wv,
    ushort_t* __restrict__ xb,  ushort_t* __restrict__ wqb,
    ushort_t* __restrict__ wkb, ushort_t* __restrict__ wvb)
{
    const int b = blockIdx.x;
    const float* src; ushort_t* dst; size_t base;
    if (b < 4096)      { src = x;  dst = xb;  base = (size_t)b * 2048; }
    else if (b < 4608) { src = wq; dst = wqb; base = (size_t)(b - 4096) * 2048; }
    else if (b < 5120) { src = wk; dst = wkb; base = (size_t)(b - 4608) * 2048; }
    else               { src = wv; dst = wvb; base = (size_t)(b - 5120) * 2048; }
    const size_t i = base + threadIdx.x * 8;
    const f32x4 a = *(const f32x4*)(src + i);
    const f32x4 c = *(const f32x4*)(src + i + 4);
    short8 o;
    o[0] = (short)f2bf(a[0]); o[1] = (short)f2bf(a[1]);
    o[2] = (short)f2bf(a[2]); o[3] = (short)f2bf(a[3]);
    o[4] = (short)f2bf(c[0]); o[5] = (short)f2bf(c[1]);
    o[6] = (short)f2bf(c[2]); o[7] = (short)f2bf(c[3]);
    *(short8*)(dst + i) = o;
}

extern "C" void kernel_launch(void* const* d_in, const int* in_sizes, int n_in,
                              void* d_out, int out_size, void* d_ws, size_t ws_size,
                              hipStream_t stream)
{
    const float* x  = (const float*)d_in[0];
    const float* Wq = (const float*)d_in[1];
    const float* bq = (const float*)d_in[2];
    const float* Wk = (const float*)d_in[3];
    const float* bk = (const float*)d_in[4];
    const float* Wv = (const float*)d_in[5];
    const float* bv = (const float*)d_in[6];
    float* out = (float*)d_out;

    char* ws = (char*)d_ws;
    const size_t MB = 1ull << 20;
    ushort_t* Xb  = (ushort_t*)(ws);
    ushort_t* Wqb = (ushort_t*)(ws + 16 * MB);
    ushort_t* Wkb = (ushort_t*)(ws + 18 * MB);
    ushort_t* Wvb = (ushort_t*)(ws + 20 * MB);
    u8*       Q8  = (u8*)(ws + 32 * MB);
    u8*       K8  = (u8*)(ws + 40 * MB);
    ushort_t* Vt  = (ushort_t*)(ws + 64 * MB);
    ushort_t* Sc  = (ushort_t*)(ws);             // reuses dead Xb/W region

    // 1) all casts in one launch
    cvt_all<<<dim3(5632), dim3(256), 0, stream>>>(
        x, Wq, Wk, Wv, Xb, Wqb, Wkb, Wvb);

    // 2) tri-fused Q,K,V projection (Q,K -> fp8; V -> Vt transposed bf16)
    qkv_gemm<<<dim3(8, 64), dim3(512), 0, stream>>>(
        Xb, Wqb, Wkb, Wvb, bq, bk, bv, Q8, K8, Vt);

    // 3) Sc = exp(Q K^T / 32), fp8 MFMA
    qk_fp8<<<dim3(16, 16, 4), dim3(256), 0, stream>>>(Q8, K8, Sc);

    // 4) out = (Sc Vt^T) / rowsum(Sc row), rowsum fused
    pv_gemm<<<dim3(8, 16, 4), dim3(256), 0, stream>>>(Sc, Vt, out);
}